// Round 2
// baseline (89.621 us; speedup 1.0000x reference)
//
#include <hip/hip_runtime.h>
#include <math.h>

#define TPB 256
#define IB 64
#define EPSF 1e-15f

// workspace layout (byte offsets into d_ws; ws_size = 256 MB)
#define P_OFF   0u                      // float2[IB*n]  = 4 MB partials
#define RD_OFF  4194304u                // float4[4096]  {R_2m, R_2m+1, d_2m, d_2m+1}
#define L2_OFF  (RD_OFF + 65536u)       // float2[4096]  {L_2m, L_2m+1}
#define RS_OFF  (L2_OFF + 32768u)       // float[8192]   scaled R
#define JL_OFF  (RS_OFF + 32768u)       // int[8192]     compacted j-list (d_j = 1)
#define LP_OFF  (JL_OFF + 32768u)       // float[32]     per-prep-block sum(L)
#define CNT_OFF (LP_OFF + 128u)         // unsigned      active-column count

__global__ void init_kernel(char* __restrict__ ws, float* __restrict__ out) {
    *(unsigned*)(ws + CNT_OFF) = 0u;
    out[0] = 0.0f;                      // harness poisons d_out
}

// Per-element precompute: Rs = (g1+log y)/(h*sqrt(2 ln 2)), d, L = exp(g2-g1).
// Also: compact the d_j=1 column indices (atomic ticket; order-free since the
// j-sum in finalize is order-independent), and per-block partial sums of L.
__global__ __launch_bounds__(TPB) void prep_kernel(
    const float* __restrict__ m_z, const float* __restrict__ y,
    const float* __restrict__ delta, char* __restrict__ ws, float inv_hk) {
    const int i = blockIdx.x * TPB + threadIdx.x;
    const float2 g = ((const float2*)m_z)[i];
    const float R = (g.x + __logf(y[i])) * inv_hk;
    const float d = delta[i];
    const float L = __expf(g.y - g.x);
    float* RD = (float*)(ws + RD_OFF);
    RD[4 * (i >> 1) + (i & 1)]     = R;
    RD[4 * (i >> 1) + 2 + (i & 1)] = d;
    ((float*)(ws + L2_OFF))[i] = L;
    ((float*)(ws + RS_OFF))[i] = R;
    if (d != 0.0f) {
        const unsigned pos = atomicAdd((unsigned*)(ws + CNT_OFF), 1u);
        ((int*)(ws + JL_OFF))[pos] = i;
    }
    float s = L;                        // block-reduce sum(L)
    for (int o = 32; o > 0; o >>= 1) s += __shfl_down(s, o, 64);
    __shared__ float wsum[TPB / 64];
    if ((threadIdx.x & 63) == 0) wsum[threadIdx.x >> 6] = s;
    __syncthreads();
    if (threadIdx.x == 0) {
        float t = 0.0f;
        for (int w = 0; w < TPB / 64; ++w) t += wsum[w];
        ((float*)(ws + LP_OFF))[blockIdx.x] = t;
    }
}

// O(n * n_active) pair kernel over compacted j-columns only (~70% of j).
// exp(-0.5*((R_i-R_j)/h)^2) = exp2(-dr^2) with dr in scaled units.
// A_t = sum_i d_i*e;  L*Phi contribution = copysign(L,dr)*(0.5-u); the global
// 0.5*sum(L) term is added once in finalize. u = upper-tail Q(|dr_true|) via
// A&S 7.1.25 3-term erfc (|eps|<=2.5e-5), reusing the SAME exp2.
__global__ __launch_bounds__(TPB, 8) void pair_kernel(
    const char* __restrict__ ws, float2* __restrict__ P, int n) {
    const unsigned cnt = *(const unsigned*)(ws + CNT_OFF);
    const int t = blockIdx.x * TPB + threadIdx.x;
    if ((unsigned)(blockIdx.x * TPB) >= cnt) return;   // uniform whole-block skip
    __shared__ float4 sRd[64];          // {R_2k, R_2k+1, d_2k, d_2k+1}
    __shared__ float2 sL2[64];          // {L_2k, L_2k+1}
    const int tid = threadIdx.x;
    const int by = blockIdx.y;
    if (tid < 64) {
        sRd[tid] = ((const float4*)(ws + RD_OFF))[(by << 6) + tid];
    } else if (tid < 128) {
        sL2[tid - 64] = ((const float2*)(ws + L2_OFF))[(by << 6) + (tid - 64)];
    }
    const int tc = min(t, (int)cnt - 1);
    const int jl = ((const int*)(ws + JL_OFF))[tc];
    const float Rj = ((const float*)(ws + RS_OFF))[jl];
    __syncthreads();

    float a0 = 0.0f, a1 = 0.0f, b0 = 0.0f, b1 = 0.0f;
#pragma unroll 4
    for (int k = 0; k < 64; ++k) {
        const float4 rd = sRd[k];                 // broadcast LDS reads
        const float2 ll = sL2[k];
        const float dr0 = rd.x - Rj;
        const float dr1 = rd.y - Rj;
        const float e0 = __builtin_amdgcn_exp2f(-(dr0 * dr0));  // exp(-drt^2/2)
        const float e1 = __builtin_amdgcn_exp2f(-(dr1 * dr1));
        const float t0 = __builtin_amdgcn_rcpf(fmaf(0.3916993f, fabsf(dr0), 1.0f));
        const float t1 = __builtin_amdgcn_rcpf(fmaf(0.3916993f, fabsf(dr1), 1.0f));
        const float u0 = t0 * fmaf(t0, fmaf(t0, 0.3739278f, -0.0479399f), 0.1740121f) * e0;
        const float u1 = t1 * fmaf(t1, fmaf(t1, 0.3739278f, -0.0479399f), 0.1740121f) * e1;
        a0 = fmaf(rd.z, e0, a0);
        a1 = fmaf(rd.w, e1, a1);
        b0 = fmaf(copysignf(ll.x, dr0), 0.5f - u0, b0);
        b1 = fmaf(copysignf(ll.y, dr1), 0.5f - u1, b1);
    }
    if (t < (int)cnt)
        P[(size_t)by * n + t] = make_float2(a0 + a1, b0 + b1);
}

// out = (1/n) * sum_{active t} (R - g2 - log(c1*A + eps) + log(invn*(B + 0.5*sumL) + eps))
__global__ __launch_bounds__(TPB) void finalize_kernel(
    const float2* __restrict__ P, const char* __restrict__ ws,
    const float* __restrict__ m_z, const float* __restrict__ y,
    float* __restrict__ out, float c1, float invn, int n) {
    const unsigned cnt = *(const unsigned*)(ws + CNT_OFF);
    const int t = blockIdx.x * TPB + threadIdx.x;
    float term = 0.0f;
    if (t < (int)cnt) {
        float sa = 0.0f, sb = 0.0f;
        for (int b = 0; b < IB; ++b) {           // coalesced float2 reads
            const float2 v = P[(size_t)b * n + t];
            sa += v.x;
            sb += v.y;
        }
        float sumL = 0.0f;
        const float* Lp = (const float*)(ws + LP_OFF);
        for (int w = 0; w < 32; ++w) sumL += Lp[w];
        const int jl = ((const int*)(ws + JL_OFF))[t];
        const float R = m_z[2 * jl] + __logf(y[jl]);
        term = R - m_z[2 * jl + 1] - __logf(fmaf(c1, sa, EPSF))
             + __logf(fmaf(invn, sb + 0.5f * sumL, EPSF));
    }
    for (int o = 32; o > 0; o >>= 1) term += __shfl_down(term, o, 64);
    __shared__ float wsum[TPB / 64];
    if ((threadIdx.x & 63) == 0) wsum[threadIdx.x >> 6] = term;
    __syncthreads();
    if (threadIdx.x == 0) {
        float ssum = 0.0f;
        for (int w = 0; w < TPB / 64; ++w) ssum += wsum[w];
        atomicAdd(out, ssum * invn);
    }
}

extern "C" void kernel_launch(void* const* d_in, const int* in_sizes, int n_in,
                              void* d_out, int out_size, void* d_ws, size_t ws_size,
                              hipStream_t stream) {
    const float* m_z   = (const float*)d_in[0];   // (n,2)
    const float* y     = (const float*)d_in[1];   // (n,1)
    const float* delta = (const float*)d_in[2];   // (n,1)
    float* out = (float*)d_out;
    const int n = in_sizes[1];                    // 8192

    char* ws = (char*)d_ws;
    float2* P = (float2*)(ws + P_OFF);

    const double h = 1.3 * pow((double)n, -0.2);
    const double k = 1.1774100225154747;          // sqrt(2 ln 2)
    const float inv_hk = (float)(1.0 / (h * k));
    const float c1 = (float)(0.3989422804014327 / ((double)n * h)); // INV_SQRT_2PI/(n*h)
    const float invn = 1.0f / (float)n;

    init_kernel<<<1, 1, 0, stream>>>(ws, out);

    const int nblk = (n + TPB - 1) / TPB;         // 32
    prep_kernel<<<nblk, TPB, 0, stream>>>(m_z, y, delta, ws, inv_hk);

    dim3 grid(nblk, IB);                          // up to 2048 blocks = 8/CU
    pair_kernel<<<grid, TPB, 0, stream>>>(ws, P, n);

    finalize_kernel<<<nblk, TPB, 0, stream>>>(P, ws, m_z, y, out, c1, invn, n);
}

// Round 3
// 85.104 us; speedup vs baseline: 1.0531x; 1.0531x over previous
//
#include <hip/hip_runtime.h>
#include <math.h>

#define TPB 256
#define IB 64
#define EPSF 1e-15f

// Fused prep + O(n^2) pair kernel (2-kernel structure: lowest launch overhead).
// Rs = (g1+log y)/(h*sqrt(2 ln 2)) so exp(-0.5*((R_i-R_j)/h)^2) = exp2(-dr^2).
// A_j = sum_i d_i*e;  L*Phi = 0.5*L + copysign(L,dr)*(0.5-u),
// u = upper-tail Q(|dr_true|) via A&S 7.1.25 3-term erfc (|eps|<=2.5e-5),
// reusing the SAME exp2. The 0.5*sum(L) over this block's span is folded in
// once (spans partition i, so the block sum telescopes to 0.5*sum_all L).
//
// This revision: (a) pinned unroll-1 two-k-iter body -- ~50 live VGPRs,
// guaranteed to fit the 64-VGPR cap of launch_bounds(256,8) with zero spill;
// (b) batched reciprocal -- one v_rcp_f32 serves all 4 A&S denominators of
// the step via prefix/suffix products (saves 3 of 4 transcendental rcps).
__global__ __launch_bounds__(TPB, 8) void pair_kernel(
    const float* __restrict__ m_z, const float* __restrict__ y,
    const float* __restrict__ delta, float2* __restrict__ P,
    float* __restrict__ out, float inv_hk, int n, int span) {
    __shared__ float4 sRd[64];    // {R_2k, R_2k+1, d_2k, d_2k+1}
    __shared__ float2 sL2[64];    // {L_2k, L_2k+1}
    __shared__ float sLtot;
    const int tid = threadIdx.x;
    const int j = blockIdx.x * TPB + tid;
    const float2* __restrict__ mz2 = (const float2*)m_z;

    const float2 gj = mz2[j];
    const float Rj = (gj.x + __logf(y[j])) * inv_hk;

    // prep this block's i-span into LDS (span == 128)
    const int ibase = blockIdx.y * span;
    if (tid < span) {
        const int i = ibase + tid;
        const float2 g = mz2[i];
        float* s = (float*)sRd;
        const int pk = tid >> 1, hf = tid & 1;
        s[4 * pk + hf]     = (g.x + __logf(y[i])) * inv_hk;
        s[4 * pk + 2 + hf] = delta[i];
        ((float*)sL2)[tid] = __expf(g.y - g.x);
    }
    __syncthreads();
    if (tid < 64) {  // wave 0: sum L over the span
        float s = 0.0f;
        for (int t = tid; t < span; t += 64) s += ((float*)sL2)[t];
        for (int o = 32; o > 0; o >>= 1) s += __shfl_down(s, o, 64);
        if (tid == 0) sLtot = s;
    }
    __syncthreads();
    if (j == 0 && blockIdx.y == 0) out[0] = 0.0f;  // harness poisons d_out

    float a0 = 0.0f, a1 = 0.0f, b0 = 0.5f * sLtot, b1 = 0.0f;
    const int m = span >> 1;                      // 64 k-iters, 2 per step
#pragma unroll 1
    for (int k = 0; k < m; k += 2) {
        const float4 rdA = sRd[k];                // broadcast LDS reads
        const float4 rdB = sRd[k + 1];
        const float2 llA = sL2[k];
        const float2 llB = sL2[k + 1];
        const float dA0 = rdA.x - Rj;
        const float dA1 = rdA.y - Rj;
        const float dB0 = rdB.x - Rj;
        const float dB1 = rdB.y - Rj;
        const float eA0 = __builtin_amdgcn_exp2f(-(dA0 * dA0));  // exp(-drt^2/2)
        const float eA1 = __builtin_amdgcn_exp2f(-(dA1 * dA1));
        const float eB0 = __builtin_amdgcn_exp2f(-(dB0 * dB0));
        const float eB1 = __builtin_amdgcn_exp2f(-(dB1 * dB1));
        // A&S denominators: 1 + p*k*|dr_s|  (p=0.33267, k=sqrt(2 ln 2))
        const float nA0 = fmaf(0.3916993f, fabsf(dA0), 1.0f);
        const float nA1 = fmaf(0.3916993f, fabsf(dA1), 1.0f);
        const float nB0 = fmaf(0.3916993f, fabsf(dB0), 1.0f);
        const float nB1 = fmaf(0.3916993f, fabsf(dB1), 1.0f);
        // batched reciprocal: t_x = 1/n_x for all four from ONE v_rcp
        const float mA = nA0 * nA1;
        const float mB = nB0 * nB1;
        const float r  = __builtin_amdgcn_rcpf(mA * mB);
        const float rA = r * mB;                  // 1/(nA0*nA1)
        const float rB = r * mA;                  // 1/(nB0*nB1)
        const float tA0 = rA * nA1, tA1 = rA * nA0;
        const float tB0 = rB * nB1, tB1 = rB * nB0;
        const float uA0 = tA0 * fmaf(tA0, fmaf(tA0, 0.3739278f, -0.0479399f), 0.1740121f) * eA0;
        const float uA1 = tA1 * fmaf(tA1, fmaf(tA1, 0.3739278f, -0.0479399f), 0.1740121f) * eA1;
        const float uB0 = tB0 * fmaf(tB0, fmaf(tB0, 0.3739278f, -0.0479399f), 0.1740121f) * eB0;
        const float uB1 = tB1 * fmaf(tB1, fmaf(tB1, 0.3739278f, -0.0479399f), 0.1740121f) * eB1;
        a0 = fmaf(rdA.z, eA0, a0);
        a1 = fmaf(rdA.w, eA1, a1);
        a0 = fmaf(rdB.z, eB0, a0);
        a1 = fmaf(rdB.w, eB1, a1);
        b0 = fmaf(copysignf(llA.x, dA0), 0.5f - uA0, b0);
        b1 = fmaf(copysignf(llA.y, dA1), 0.5f - uA1, b1);
        b0 = fmaf(copysignf(llB.x, dB0), 0.5f - uB0, b0);
        b1 = fmaf(copysignf(llB.y, dB1), 0.5f - uB1, b1);
    }
    P[(size_t)blockIdx.y * n + j] = make_float2(a0 + a1, b0 + b1);
}

// out = (1/n) * sum_j d_j * (R_j - g2_j - log(c1*A_j + eps) + log(invn*B_j + eps))
__global__ __launch_bounds__(TPB) void finalize_kernel(
    const float2* __restrict__ P, const float* __restrict__ m_z,
    const float* __restrict__ y, const float* __restrict__ delta,
    float* __restrict__ out, float c1, float invn, int n) {
    const int j = blockIdx.x * TPB + threadIdx.x;
    float sa = 0.0f, sb = 0.0f;
    for (int b = 0; b < IB; ++b) {               // coalesced float2 reads
        const float2 v = P[(size_t)b * n + j];
        sa += v.x;
        sb += v.y;
    }
    const float d = delta[j];
    const float R = m_z[2 * j] + __logf(y[j]);
    float term = d * (R - m_z[2 * j + 1] - __logf(fmaf(c1, sa, EPSF))
                                         + __logf(fmaf(invn, sb, EPSF)));
    for (int o = 32; o > 0; o >>= 1) term += __shfl_down(term, o, 64);
    __shared__ float wsum[TPB / 64];
    if ((threadIdx.x & 63) == 0) wsum[threadIdx.x >> 6] = term;
    __syncthreads();
    if (threadIdx.x == 0) {
        float ssum = 0.0f;
        for (int w = 0; w < TPB / 64; ++w) ssum += wsum[w];
        atomicAdd(out, ssum * invn);
    }
}

extern "C" void kernel_launch(void* const* d_in, const int* in_sizes, int n_in,
                              void* d_out, int out_size, void* d_ws, size_t ws_size,
                              hipStream_t stream) {
    const float* m_z   = (const float*)d_in[0];   // (n,2)
    const float* y     = (const float*)d_in[1];   // (n,1)
    const float* delta = (const float*)d_in[2];   // (n,1)
    float* out = (float*)d_out;
    const int n = in_sizes[1];                    // 8192

    float2* P = (float2*)d_ws;                    // IB * n * 8 B = 4 MB

    const double h = 1.3 * pow((double)n, -0.2);
    const double k = 1.1774100225154747;          // sqrt(2 ln 2)
    const float inv_hk = (float)(1.0 / (h * k));
    const float c1 = (float)(0.3989422804014327 / ((double)n * h)); // INV_SQRT_2PI/(n*h)
    const float invn = 1.0f / (float)n;
    const int span = n / IB;                      // 128

    const int nblk = (n + TPB - 1) / TPB;         // 32
    dim3 grid(nblk, IB);                          // 2048 blocks = 8/CU
    pair_kernel<<<grid, TPB, 0, stream>>>(m_z, y, delta, P, out, inv_hk, n, span);
    finalize_kernel<<<nblk, TPB, 0, stream>>>(P, m_z, y, delta, out, c1, invn, n);
}